// Round 16
// baseline (398.236 us; speedup 1.0000x reference)
//
#include <hip/hip_runtime.h>

#define S_SP   13824        // 24*24*24 spatial
#define CHAN   256
#define NQ     27648        // 2 * 13824
#define KCODES 2048
#define CS     3538944      // CHAN * S_SP
#define OFF_Q   1
#define OFF_PPL 7077889
#define OFF_ENC 7077890LL
#define OFF_IDX 63700994LL

typedef __bf16 bf16x8 __attribute__((ext_vector_type(8)));
typedef float  f32x4  __attribute__((ext_vector_type(4)));

__device__ __forceinline__ unsigned int f2bf(float f) {
  unsigned int u = __float_as_uint(f);
  unsigned int r = u + 0x7FFFu + ((u >> 16) & 1u);   // RNE
  return r >> 16;
}
__device__ __forceinline__ float bf2f(unsigned int h) {
  return __uint_as_float(h << 16);
}
__device__ __forceinline__ void fsplit(float f, unsigned int& hi, unsigned int& lo) {
  hi = f2bf(f);
  float r = f - bf2f(hi);
  lo = f2bf(r);
}

// ---------------- prep_wx: fused W-prep (blocks 0..255) and X-prep (blocks 256..1119) ----------------
__global__ __launch_bounds__(256) void prep_wx(const float* __restrict__ W,
                                               const float* __restrict__ X,
                                               unsigned short* __restrict__ Wh,
                                               unsigned short* __restrict__ Wl,
                                               float* __restrict__ wn,
                                               unsigned short* __restrict__ Xh,
                                               unsigned short* __restrict__ Xl,
                                               float* __restrict__ xn,
                                               int* __restrict__ zero_base) {
  __shared__ float xs[32 * 257];
  int t = threadIdx.x;
  if (blockIdx.x < 256) {
    // ---- W path ----
    if (blockIdx.x == 0) {
      for (int j = t; j < 2050; j += 256) zero_base[j] = 0;
    }
    int g = blockIdx.x * 256 + t;
    int row = g >> 5;
    int d0 = (g & 31) * 8;
    const float* Wp = W + (size_t)row * CHAN + d0;
    float v[8];
    *(float4*)(v) = *(const float4*)Wp;
    *(float4*)(v + 4) = *(const float4*)(Wp + 4);
    float s = 0.f;
    unsigned int h[8], l[8];
#pragma unroll
    for (int j = 0; j < 8; ++j) {
      s = fmaf(v[j], v[j], s);
      fsplit(v[j], h[j], l[j]);
    }
    int4 ph, pl;
    ph.x = (int)(h[0] | (h[1] << 16)); ph.y = (int)(h[2] | (h[3] << 16));
    ph.z = (int)(h[4] | (h[5] << 16)); ph.w = (int)(h[6] | (h[7] << 16));
    pl.x = (int)(l[0] | (l[1] << 16)); pl.y = (int)(l[2] | (l[3] << 16));
    pl.z = (int)(l[4] | (l[5] << 16)); pl.w = (int)(l[6] | (l[7] << 16));
    *(int4*)(Wh + (size_t)row * CHAN + d0) = ph;
    *(int4*)(Wl + (size_t)row * CHAN + d0) = pl;
    for (int off = 16; off; off >>= 1) s += __shfl_down(s, off);
    if ((t & 31) == 0) wn[row] = s;
    return;
  }
  // ---- X path ----
  int qb = (blockIdx.x - 256) * 32;
  int b = qb / S_SP, s0 = qb % S_SP;
  const float* xp = X + (size_t)b * CS + s0;
  int q = t & 31;
  int db = t >> 5;                 // 0..7
  for (int r = 0; r < 32; ++r) {
    int d = db + (r << 3);
    xs[q * 257 + d] = xp[(size_t)d * S_SP + q];
  }
  __syncthreads();
  int row = t >> 3, c8 = t & 7;
  size_t obase = (size_t)(qb + row) * CHAN;
  const float* rp0 = xs + row * 257;
  float ss = 0.f;
#pragma unroll
  for (int j = 0; j < 4; ++j) {
    int d = j * 64 + c8 * 8;
    const float* rp = rp0 + d;
    unsigned int h[8], l[8];
#pragma unroll
    for (int e = 0; e < 8; ++e) {
      float v = rp[e];
      ss = fmaf(v, v, ss);
      fsplit(v, h[e], l[e]);
    }
    int4 ph, pl;
    ph.x = (int)(h[0] | (h[1] << 16)); ph.y = (int)(h[2] | (h[3] << 16));
    ph.z = (int)(h[4] | (h[5] << 16)); ph.w = (int)(h[6] | (h[7] << 16));
    pl.x = (int)(l[0] | (l[1] << 16)); pl.y = (int)(l[2] | (l[3] << 16));
    pl.z = (int)(l[4] | (l[5] << 16)); pl.w = (int)(l[6] | (l[7] << 16));
    *(int4*)(Xh + obase + d) = ph;
    *(int4*)(Xl + obase + d) = pl;
  }
  ss += __shfl_xor(ss, 1);
  ss += __shfl_xor(ss, 2);
  ss += __shfl_xor(ss, 4);
  if (c8 == 0) xn[qb + row] = ss;
}

// ---------------- dist_mfma: register-staged, barrier-free split-bf16 MFMA ----------------
// 4 waves x 32 q = 128 q/block; kg = blockIdx&1 picks 1024-code half.
// B-fragments loaded straight from L2 into a 4-slot circular register buffer
// (slot = c&3, all compile-time). W hi+lo = 2 MB, L2-resident. Zero barriers
// in the K-loop; same MFMA sequence/values as the LDS version (identical numerics).
__global__ __launch_bounds__(256, 2) void dist_mfma(const unsigned short* __restrict__ Xh,
                                                    const unsigned short* __restrict__ Xl,
                                                    const unsigned short* __restrict__ Wh,
                                                    const unsigned short* __restrict__ Wl,
                                                    const float* __restrict__ wn,
                                                    float* __restrict__ rB1,
                                                    int* __restrict__ rI1,
                                                    float* __restrict__ rB2) {
  __shared__ float wnl[1024];
  int t = threadIdx.x;
  int w = t >> 6, l = t & 63;
  int lr = l & 15, lc = l >> 4;
  int kg = blockIdx.x & 1;
  int qb = (blockIdx.x >> 1) * 128;
  int kofs = kg << 10;

  for (int j = t; j < 1024; j += 256) wnl[j] = wn[kofs + j];

  bf16x8 ah[2][8], al[2][8];
#pragma unroll
  for (int s = 0; s < 2; ++s) {
    size_t base = (size_t)(qb + w * 32 + s * 16 + lr) * CHAN + lc * 8;
#pragma unroll
    for (int c = 0; c < 8; ++c) {
      ah[s][c] = *(const bf16x8*)(Xh + base + c * 32);
      al[s][c] = *(const bf16x8*)(Xl + base + c * 32);
    }
  }

  float b1[2][4], b2[2][4]; int i1[2][4];
#pragma unroll
  for (int s = 0; s < 2; ++s)
#pragma unroll
    for (int r = 0; r < 4; ++r) { b1[s][r] = 3.4e38f; b2[s][r] = 3.4e38f; i1[s][r] = 0; }

  auto select = [&](const f32x4& a0, const f32x4& a1, int k, float wnk) {
#pragma unroll
    for (int r = 0; r < 4; ++r) {
      float s0 = fmaf(-2.0f, a0[r], wnk);
      bool lt0 = s0 < b1[0][r];
      b2[0][r] = fminf(b2[0][r], fmaxf(s0, b1[0][r]));
      b1[0][r] = lt0 ? s0 : b1[0][r];
      i1[0][r] = lt0 ? k : i1[0][r];
      float s1 = fmaf(-2.0f, a1[r], wnk);
      bool lt1 = s1 < b1[1][r];
      b2[1][r] = fminf(b2[1][r], fmaxf(s1, b1[1][r]));
      b1[1][r] = lt1 ? s1 : b1[1][r];
      i1[1][r] = lt1 ? k : i1[1][r];
    }
  };

  __syncthreads();                  // wnl ready (only barrier in the kernel)

  const unsigned short* ph  = Wh + (size_t)(kofs + lr) * CHAN + lc * 8;
  const unsigned short* pl_ = Wl + (size_t)(kofs + lr) * CHAN + lc * 8;

  // 4-slot circular chunk buffer; prologue: chunks 0..3 of tile 0
  bf16x8 bh[4], bl[4];
#pragma unroll
  for (int c = 0; c < 4; ++c) {
    bh[c] = *(const bf16x8*)(ph + c * 32);
    bl[c] = *(const bf16x8*)(pl_ + c * 32);
  }

  f32x4 pa0, pa1;
  int   pk = 0;
  float pwnk = 0.f;

  for (int kt = 0; kt < 64; ++kt) {
    f32x4 a0 = {0.f, 0.f, 0.f, 0.f}, a1 = {0.f, 0.f, 0.f, 0.f};
#pragma unroll
    for (int c = 0; c < 8; ++c) {
      const int sl = c & 3;         // compile-time slot
      a0 = __builtin_amdgcn_mfma_f32_16x16x32_bf16(ah[0][c], bh[sl], a0, 0, 0, 0);
      a1 = __builtin_amdgcn_mfma_f32_16x16x32_bf16(ah[1][c], bh[sl], a1, 0, 0, 0);
      a0 = __builtin_amdgcn_mfma_f32_16x16x32_bf16(al[0][c], bh[sl], a0, 0, 0, 0);
      a1 = __builtin_amdgcn_mfma_f32_16x16x32_bf16(al[1][c], bh[sl], a1, 0, 0, 0);
      a0 = __builtin_amdgcn_mfma_f32_16x16x32_bf16(ah[0][c], bl[sl], a0, 0, 0, 0);
      a1 = __builtin_amdgcn_mfma_f32_16x16x32_bf16(ah[1][c], bl[sl], a1, 0, 0, 0);
      // refill slot with the chunk 4 ahead: (kt, c+4) for c<4, (kt+1, c-4) for c>=4
      if (c < 4) {
        bh[sl] = *(const bf16x8*)(ph + (c + 4) * 32);
        bl[sl] = *(const bf16x8*)(pl_ + (c + 4) * 32);
      } else {
        bh[sl] = *(const bf16x8*)(ph + 16 * CHAN + (c - 4) * 32);
        bl[sl] = *(const bf16x8*)(pl_ + 16 * CHAN + (c - 4) * 32);
      }
    }
    if (kt) select(pa0, pa1, pk, pwnk);
    pa0 = a0; pa1 = a1;
    pk = kofs + (kt << 4) + lr;
    pwnk = wnl[(kt << 4) + lr];
    ph  += 16 * CHAN;
    pl_ += 16 * CHAN;
  }
  select(pa0, pa1, pk, pwnk);

#pragma unroll
  for (int m = 1; m < 16; m <<= 1) {
#pragma unroll
    for (int s = 0; s < 2; ++s)
#pragma unroll
      for (int r = 0; r < 4; ++r) {
        float ob1 = __shfl_xor(b1[s][r], m);
        int   oi  = __shfl_xor(i1[s][r], m);
        float ob2 = __shfl_xor(b2[s][r], m);
        bool sw = (ob1 < b1[s][r]) || (ob1 == b1[s][r] && oi < i1[s][r]);
        b2[s][r] = fminf(fmaxf(b1[s][r], ob1), fminf(b2[s][r], ob2));
        b1[s][r] = sw ? ob1 : b1[s][r];
        i1[s][r] = sw ? oi : i1[s][r];
      }
  }
  if (lr == 0) {
#pragma unroll
    for (int s = 0; s < 2; ++s)
#pragma unroll
      for (int r = 0; r < 4; ++r) {
        int q = qb + w * 32 + s * 16 + lc * 4 + r;
        size_t o = (size_t)kg * NQ + q;
        rB1[o] = b1[s][r]; rI1[o] = i1[s][r]; rB2[o] = b2[s][r];
      }
  }
}

// ---------------- merge_k: combine kg halves, idx + flags + counts + loss ----------------
__global__ __launch_bounds__(256) void merge_k(const float* __restrict__ rB1,
                                               const int* __restrict__ rI1,
                                               const float* __restrict__ rB2,
                                               const float* __restrict__ xn,
                                               float* __restrict__ idx_out,
                                               int* __restrict__ flagcount,
                                               int2* __restrict__ flaglist,
                                               int* __restrict__ counts,
                                               float* __restrict__ loss_acc) {
  __shared__ float wred[4];
  int t = threadIdx.x;
  int n = blockIdx.x * 256 + t;
  float B1 = rB1[n]; int I1 = rI1[n]; float B2 = rB2[n];
  float c1 = rB1[NQ + n]; int ci = rI1[NQ + n]; float c2 = rB2[NQ + n];
  bool sw = (c1 < B1) || (c1 == B1 && ci < I1);
  float nb2 = fminf(fmaxf(B1, c1), fminf(B2, c2));
  float nb1 = sw ? c1 : B1;
  int   ni  = sw ? ci : I1;
  if (nb2 - nb1 < 0.05f) {
    int slot = atomicAdd(flagcount, 1);
    flaglist[slot] = make_int2(n, ni);
  }
  idx_out[n] = (float)ni;   // provisional if flagged; refine2 overwrites
  atomicAdd(&counts[ni], 1);

  // loss: dist^2 = ||x||^2 + wn - 2 x.w = xn + best_score
  float lq = xn[n] + nb1;
  for (int off = 32; off; off >>= 1) lq += __shfl_down(lq, off);
  if ((t & 63) == 0) wred[t >> 6] = lq;
  __syncthreads();
  if (t == 0) atomicAdd(loss_acc, wred[0] + wred[1] + wred[2] + wred[3]);
}

// ---------------- refine2: fp64 exact re-scan of flagged queries + count patch ----------------
__global__ __launch_bounds__(256) void refine2(const float* __restrict__ X,
                                               const float* __restrict__ W,
                                               const int* __restrict__ flagcount,
                                               const int2* __restrict__ flaglist,
                                               float* __restrict__ idx_out,
                                               int* __restrict__ counts) {
  __shared__ double xd[CHAN];
  __shared__ double rv[256];
  __shared__ int    ri[256];
  int t = threadIdx.x;
  int cnt = flagcount[0];
  for (int jj = blockIdx.x; jj < cnt; jj += gridDim.x) {
    __syncthreads();
    int2 e = flaglist[jj];
    int n = e.x, prov = e.y;
    int b = n / S_SP, s = n % S_SP;
    xd[t] = (double)X[(size_t)b * CS + (size_t)t * S_SP + s];
    __syncthreads();

    double best = 1e300;
    int bi = 1 << 30;
    for (int j8 = 0; j8 < 8; ++j8) {
      int k = t * 8 + j8;
      const float* Wp = W + (size_t)k * CHAN;
      double dsum = 0.0;
      for (int d = 0; d < CHAN; ++d) {
        double df = xd[d] - (double)Wp[d];
        dsum = fma(df, df, dsum);
      }
      if (dsum < best) { best = dsum; bi = k; }
    }
    rv[t] = best; ri[t] = bi;
    __syncthreads();
    for (int off = 128; off > 0; off >>= 1) {
      if (t < off) {
        if (rv[t + off] < rv[t] || (rv[t + off] == rv[t] && ri[t + off] < ri[t])) {
          rv[t] = rv[t + off]; ri[t] = ri[t + off];
        }
      }
      __syncthreads();
    }
    if (t == 0) {
      int fin = ri[0];
      idx_out[n] = (float)fin;
      if (fin != prov) {
        atomicAdd(&counts[prov], -1);
        atomicAdd(&counts[fin], 1);
      }
    }
  }
}

// ---------------- emit_q: one-hot rows (zeros then ones) + quantized gather ----------------
__global__ __launch_bounds__(256) void emit_q(const float* __restrict__ W,
                                              float* __restrict__ outF) {
  __shared__ int sidx[64];
  int t = threadIdx.x;
  int qb = blockIdx.x * 64;
  if (t < 64) sidx[t] = (int)outF[OFF_IDX + qb + t];
  __syncthreads();

  // zero all 64 rows: 2 float4 stores per row per thread, wave-contiguous 1KB
  {
    f32x4 z = {0.f, 0.f, 0.f, 0.f};
    float* rp = outF + OFF_ENC + (size_t)qb * KCODES + t * 4;
#pragma unroll 4
    for (int q = 0; q < 64; ++q) {
      *(f32x4*)rp = z;
      *(f32x4*)(rp + 1024) = z;
      rp += KCODES;
    }
  }
  __syncthreads();   // order zeros before ones
  if (t < 64) outF[OFF_ENC + (size_t)(qb + t) * KCODES + sidx[t]] = 1.0f;

  // quantized gather (4 channel-groups x 64 queries)
  int q = t & 63, cg = t >> 6;
  int n = qb + q;
  int idx = sidx[q];
  int b = n / S_SP, s = n % S_SP;   // 13824 % 64 == 0: block never crosses b
  const float* Wp = W + (size_t)idx * CHAN;
  float* qp = outF + OFF_Q + (size_t)b * CS + s;
#pragma unroll 8
  for (int k = 0; k < 64; ++k) {
    int c = cg + (k << 2);
    qp[(size_t)c * S_SP] = Wp[c];
  }
}

// ---------------- finalize ----------------
__global__ __launch_bounds__(256) void finalize(const int* __restrict__ counts,
                                                const float* __restrict__ loss_acc,
                                                float* __restrict__ outF) {
  __shared__ double red[256];
  int t = threadIdx.x;
  double H = 0.0;
  for (int k = t; k < KCODES; k += 256) {
    double p = (double)counts[k] / (double)NQ;
    H += p * log(p + 1e-10);
  }
  red[t] = H;
  __syncthreads();
  for (int off = 128; off > 0; off >>= 1) {
    if (t < off) red[t] += red[t + off];
    __syncthreads();
  }
  if (t == 0) {
    outF[0] = 0.25f * (loss_acc[0] / 7077888.0f);
    outF[OFF_PPL] = (float)exp(-red[0]);
  }
}

extern "C" void kernel_launch(void* const* d_in, const int* in_sizes, int n_in,
                              void* d_out, int out_size, void* d_ws, size_t ws_size,
                              hipStream_t stream) {
  const float* X = (const float*)d_in[0];
  const float* W = (const float*)d_in[1];
  float* outF = (float*)d_out;
  char* ws = (char*)d_ws;
  float* wn        = (float*)ws;                    // 8 KB
  int*   counts    = (int*)(ws + 8192);             // 8 KB   [zeroed by prep_wx]
  float* loss_acc  = (float*)(ws + 16384);          // 4 B    [zeroed by prep_wx]
  int*   flagcount = (int*)(ws + 16388);            // 4 B    [zeroed by prep_wx]
  int2*  flaglist  = (int2*)(ws + 32768);           // 8*NQ = 216 KB
  float* rB1       = (float*)(ws + 262144);         // 2*NQ*4
  int*   rI1       = (int*)(ws + 483328);           // 2*NQ*4
  float* rB2       = (float*)(ws + 704512);         // 2*NQ*4
  float* xn        = (float*)(ws + 925696);         // NQ*4 = 108 KB
  unsigned short* Wh = (unsigned short*)(ws + 1048576);   // 1 MB
  unsigned short* Wl = (unsigned short*)(ws + 2097152);   // 1 MB
  unsigned short* Xh = (unsigned short*)(ws + 3145728);   // 14.16 MB
  unsigned short* Xl = Xh + (size_t)NQ * CHAN;            // 14.16 MB

  prep_wx<<<256 + NQ / 32, 256, 0, stream>>>(W, X, Wh, Wl, wn, Xh, Xl, xn,
                                             (int*)(ws + 8192));
  dist_mfma<<<(NQ / 128) * 2, 256, 0, stream>>>(Xh, Xl, Wh, Wl, wn, rB1, rI1, rB2);
  merge_k<<<NQ / 256, 256, 0, stream>>>(rB1, rI1, rB2, xn, outF + OFF_IDX,
                                        flagcount, flaglist, counts, loss_acc);
  refine2<<<256, 256, 0, stream>>>(X, W, flagcount, flaglist, outF + OFF_IDX, counts);
  emit_q<<<NQ / 64, 256, 0, stream>>>(W, outF);
  finalize<<<1, 256, 0, stream>>>(counts, loss_acc, outF);
}

// Round 17
// 257.351 us; speedup vs baseline: 1.5474x; 1.5474x over previous
//
#include <hip/hip_runtime.h>

#define S_SP   13824        // 24*24*24 spatial
#define CHAN   256
#define NQ     27648        // 2 * 13824
#define KCODES 2048
#define CS     3538944      // CHAN * S_SP
#define OFF_Q   1
#define OFF_PPL 7077889
#define OFF_ENC 7077890LL
#define OFF_IDX 63700994LL

typedef __bf16 bf16x8 __attribute__((ext_vector_type(8)));
typedef float  f32x4  __attribute__((ext_vector_type(4)));

#define GLOAD_LDS16(g, s)                                                      \
  __builtin_amdgcn_global_load_lds(                                            \
      (const __attribute__((address_space(1))) void*)(g),                      \
      (__attribute__((address_space(3))) void*)(s), 16, 0, 0)

__device__ __forceinline__ unsigned int f2bf(float f) {
  unsigned int u = __float_as_uint(f);
  unsigned int r = u + 0x7FFFu + ((u >> 16) & 1u);   // RNE
  return r >> 16;
}
__device__ __forceinline__ float bf2f(unsigned int h) {
  return __uint_as_float(h << 16);
}
__device__ __forceinline__ void fsplit(float f, unsigned int& hi, unsigned int& lo) {
  hi = f2bf(f);
  float r = f - bf2f(hi);
  lo = f2bf(r);
}

// ---------------- prep_wx: W-prep (0..255), X-prep (256..1119), ENC-zero (1120..2847) ----------------
__global__ __launch_bounds__(256) void prep_wx(const float* __restrict__ W,
                                               const float* __restrict__ X,
                                               unsigned short* __restrict__ Wh,
                                               unsigned short* __restrict__ Wl,
                                               float* __restrict__ wn,
                                               unsigned short* __restrict__ Xh,
                                               unsigned short* __restrict__ Xl,
                                               float* __restrict__ xn,
                                               int* __restrict__ zero_base,
                                               float* __restrict__ outF) {
  __shared__ float xs[32 * 257];
  int t = threadIdx.x;
  if (blockIdx.x >= 1120) {
    // ---- ENC zero path: 1728 blocks x 16 rows, wave-contiguous float4 stores ----
    int bid2 = blockIdx.x - 1120;
    f32x4 z = {0.f, 0.f, 0.f, 0.f};
    float* rp = outF + OFF_ENC + (size_t)bid2 * 16 * KCODES + t * 4;
#pragma unroll 4
    for (int q = 0; q < 16; ++q) {
      *(f32x4*)rp = z;
      *(f32x4*)(rp + 1024) = z;
      rp += KCODES;
    }
    return;
  }
  if (blockIdx.x < 256) {
    // ---- W path ----
    if (blockIdx.x == 0) {
      for (int j = t; j < 2050; j += 256) zero_base[j] = 0;
    }
    int g = blockIdx.x * 256 + t;
    int row = g >> 5;
    int d0 = (g & 31) * 8;
    const float* Wp = W + (size_t)row * CHAN + d0;
    float v[8];
    *(float4*)(v) = *(const float4*)Wp;
    *(float4*)(v + 4) = *(const float4*)(Wp + 4);
    float s = 0.f;
    unsigned int h[8], l[8];
#pragma unroll
    for (int j = 0; j < 8; ++j) {
      s = fmaf(v[j], v[j], s);
      fsplit(v[j], h[j], l[j]);
    }
    int4 ph, pl;
    ph.x = (int)(h[0] | (h[1] << 16)); ph.y = (int)(h[2] | (h[3] << 16));
    ph.z = (int)(h[4] | (h[5] << 16)); ph.w = (int)(h[6] | (h[7] << 16));
    pl.x = (int)(l[0] | (l[1] << 16)); pl.y = (int)(l[2] | (l[3] << 16));
    pl.z = (int)(l[4] | (l[5] << 16)); pl.w = (int)(l[6] | (l[7] << 16));
    *(int4*)(Wh + (size_t)row * CHAN + d0) = ph;
    *(int4*)(Wl + (size_t)row * CHAN + d0) = pl;
    for (int off = 16; off; off >>= 1) s += __shfl_down(s, off);
    if ((t & 31) == 0) wn[row] = s;
    return;
  }
  // ---- X path ----
  int qb = (blockIdx.x - 256) * 32;
  int b = qb / S_SP, s0 = qb % S_SP;
  const float* xp = X + (size_t)b * CS + s0;
  int q = t & 31;
  int db = t >> 5;                 // 0..7
  for (int r = 0; r < 32; ++r) {
    int d = db + (r << 3);
    xs[q * 257 + d] = xp[(size_t)d * S_SP + q];
  }
  __syncthreads();
  int row = t >> 3, c8 = t & 7;
  size_t obase = (size_t)(qb + row) * CHAN;
  const float* rp0 = xs + row * 257;
  float ss = 0.f;
#pragma unroll
  for (int j = 0; j < 4; ++j) {
    int d = j * 64 + c8 * 8;
    const float* rp = rp0 + d;
    unsigned int h[8], l[8];
#pragma unroll
    for (int e = 0; e < 8; ++e) {
      float v = rp[e];
      ss = fmaf(v, v, ss);
      fsplit(v, h[e], l[e]);
    }
    int4 ph, pl;
    ph.x = (int)(h[0] | (h[1] << 16)); ph.y = (int)(h[2] | (h[3] << 16));
    ph.z = (int)(h[4] | (h[5] << 16)); ph.w = (int)(h[6] | (h[7] << 16));
    pl.x = (int)(l[0] | (l[1] << 16)); pl.y = (int)(l[2] | (l[3] << 16));
    pl.z = (int)(l[4] | (l[5] << 16)); pl.w = (int)(l[6] | (l[7] << 16));
    *(int4*)(Xh + obase + d) = ph;
    *(int4*)(Xl + obase + d) = pl;
  }
  ss += __shfl_xor(ss, 1);
  ss += __shfl_xor(ss, 2);
  ss += __shfl_xor(ss, 4);
  if (c8 == 0) xn[qb + row] = ss;
}

// ---------------- dist_mfma: LDS-staged split-bf16 MFMA, pipelined argmin (r13) ----------------
// 2-way code split; selection for tile kt-1 overlaps tile kt's MFMAs; setprio around MFMA cluster.
__global__ __launch_bounds__(256, 2) void dist_mfma(const unsigned short* __restrict__ Xh,
                                                    const unsigned short* __restrict__ Xl,
                                                    const unsigned short* __restrict__ Wh,
                                                    const unsigned short* __restrict__ Wl,
                                                    const float* __restrict__ wn,
                                                    float* __restrict__ rB1,
                                                    int* __restrict__ rI1,
                                                    float* __restrict__ rB2) {
  __shared__ __align__(16) unsigned short sW[2][2][4096]; // [buf][hi/lo][chunk*512 + lane*8]
  __shared__ float wnl[1024];
  int t = threadIdx.x;
  int w = t >> 6, l = t & 63;
  int lr = l & 15, lc = l >> 4;
  int kg = blockIdx.x & 1;
  int qb = (blockIdx.x >> 1) * 128;
  int kofs = kg << 10;

  for (int j = t; j < 1024; j += 256) wnl[j] = wn[kofs + j];

  bf16x8 ah[2][8], al[2][8];
#pragma unroll
  for (int s = 0; s < 2; ++s) {
    size_t base = (size_t)(qb + w * 32 + s * 16 + lr) * CHAN + lc * 8;
#pragma unroll
    for (int c = 0; c < 8; ++c) {
      ah[s][c] = *(const bf16x8*)(Xh + base + c * 32);
      al[s][c] = *(const bf16x8*)(Xl + base + c * 32);
    }
  }

  float b1[2][4], b2[2][4]; int i1[2][4];
#pragma unroll
  for (int s = 0; s < 2; ++s)
#pragma unroll
    for (int r = 0; r < 4; ++r) { b1[s][r] = 3.4e38f; b2[s][r] = 3.4e38f; i1[s][r] = 0; }

  auto stage = [&](int buf, int kt) {
    size_t rb = (size_t)(kofs + (kt << 4) + lr) * CHAN + lc * 8;
    GLOAD_LDS16(Wh + rb + w * 32,        &sW[buf][0][w * 512]);
    GLOAD_LDS16(Wh + rb + (w + 4) * 32,  &sW[buf][0][(w + 4) * 512]);
    GLOAD_LDS16(Wl + rb + w * 32,        &sW[buf][1][w * 512]);
    GLOAD_LDS16(Wl + rb + (w + 4) * 32,  &sW[buf][1][(w + 4) * 512]);
  };

  auto compute = [&](int cur, f32x4& o0, f32x4& o1) {
    f32x4 a0 = {0.f, 0.f, 0.f, 0.f}, a1 = {0.f, 0.f, 0.f, 0.f};
    __builtin_amdgcn_s_setprio(1);
#pragma unroll
    for (int c = 0; c < 8; ++c) {
      bf16x8 bh = *(const bf16x8*)&sW[cur][0][c * 512 + (l << 3)];
      bf16x8 bl = *(const bf16x8*)&sW[cur][1][c * 512 + (l << 3)];
      a0 = __builtin_amdgcn_mfma_f32_16x16x32_bf16(ah[0][c], bh, a0, 0, 0, 0);
      a1 = __builtin_amdgcn_mfma_f32_16x16x32_bf16(ah[1][c], bh, a1, 0, 0, 0);
      a0 = __builtin_amdgcn_mfma_f32_16x16x32_bf16(al[0][c], bh, a0, 0, 0, 0);
      a1 = __builtin_amdgcn_mfma_f32_16x16x32_bf16(al[1][c], bh, a1, 0, 0, 0);
      a0 = __builtin_amdgcn_mfma_f32_16x16x32_bf16(ah[0][c], bl, a0, 0, 0, 0);
      a1 = __builtin_amdgcn_mfma_f32_16x16x32_bf16(ah[1][c], bl, a1, 0, 0, 0);
    }
    __builtin_amdgcn_s_setprio(0);
    o0 = a0; o1 = a1;
  };

  auto select = [&](const f32x4& a0, const f32x4& a1, int k, float wnk) {
#pragma unroll
    for (int r = 0; r < 4; ++r) {
      float s0 = fmaf(-2.0f, a0[r], wnk);
      bool lt0 = s0 < b1[0][r];
      b2[0][r] = fminf(b2[0][r], fmaxf(s0, b1[0][r]));
      b1[0][r] = lt0 ? s0 : b1[0][r];
      i1[0][r] = lt0 ? k : i1[0][r];
      float s1 = fmaf(-2.0f, a1[r], wnk);
      bool lt1 = s1 < b1[1][r];
      b2[1][r] = fminf(b2[1][r], fmaxf(s1, b1[1][r]));
      b1[1][r] = lt1 ? s1 : b1[1][r];
      i1[1][r] = lt1 ? k : i1[1][r];
    }
  };

  stage(0, 0);
  __syncthreads();

  // prologue: compute tile 0 while tile 1 stages
  f32x4 pa0, pa1;
  int   pk   = kofs + lr;
  float pwnk = wnl[lr];
  stage(1, 1);
  compute(0, pa0, pa1);
  __syncthreads();

  for (int kt = 1; kt < 64; ++kt) {
    int cur = kt & 1;
    if (kt < 63) stage(cur ^ 1, kt + 1);
    f32x4 a0, a1;
    compute(cur, a0, a1);
    // selection for previous tile — independent of this tile's MFMA chain
    select(pa0, pa1, pk, pwnk);
    pa0 = a0; pa1 = a1;
    pk = kofs + (kt << 4) + lr;
    pwnk = wnl[(kt << 4) + lr];
    __syncthreads();
  }
  select(pa0, pa1, pk, pwnk);

#pragma unroll
  for (int m = 1; m < 16; m <<= 1) {
#pragma unroll
    for (int s = 0; s < 2; ++s)
#pragma unroll
      for (int r = 0; r < 4; ++r) {
        float ob1 = __shfl_xor(b1[s][r], m);
        int   oi  = __shfl_xor(i1[s][r], m);
        float ob2 = __shfl_xor(b2[s][r], m);
        bool sw = (ob1 < b1[s][r]) || (ob1 == b1[s][r] && oi < i1[s][r]);
        b2[s][r] = fminf(fmaxf(b1[s][r], ob1), fminf(b2[s][r], ob2));
        b1[s][r] = sw ? ob1 : b1[s][r];
        i1[s][r] = sw ? oi : i1[s][r];
      }
  }
  if (lr == 0) {
#pragma unroll
    for (int s = 0; s < 2; ++s)
#pragma unroll
      for (int r = 0; r < 4; ++r) {
        int q = qb + w * 32 + s * 16 + lc * 4 + r;
        size_t o = (size_t)kg * NQ + q;
        rB1[o] = b1[s][r]; rI1[o] = i1[s][r]; rB2[o] = b2[s][r];
      }
  }
}

// ---------------- merge_k: combine kg halves, idx + flags + counts + loss ----------------
__global__ __launch_bounds__(256) void merge_k(const float* __restrict__ rB1,
                                               const int* __restrict__ rI1,
                                               const float* __restrict__ rB2,
                                               const float* __restrict__ xn,
                                               float* __restrict__ idx_out,
                                               int* __restrict__ flagcount,
                                               int2* __restrict__ flaglist,
                                               int* __restrict__ counts,
                                               float* __restrict__ loss_acc) {
  __shared__ float wred[4];
  int t = threadIdx.x;
  int n = blockIdx.x * 256 + t;
  float B1 = rB1[n]; int I1 = rI1[n]; float B2 = rB2[n];
  float c1 = rB1[NQ + n]; int ci = rI1[NQ + n]; float c2 = rB2[NQ + n];
  bool sw = (c1 < B1) || (c1 == B1 && ci < I1);
  float nb2 = fminf(fmaxf(B1, c1), fminf(B2, c2));
  float nb1 = sw ? c1 : B1;
  int   ni  = sw ? ci : I1;
  if (nb2 - nb1 < 0.05f) {
    int slot = atomicAdd(flagcount, 1);
    flaglist[slot] = make_int2(n, ni);
  }
  idx_out[n] = (float)ni;   // provisional if flagged; refine2 overwrites
  atomicAdd(&counts[ni], 1);

  // loss: dist^2 = ||x||^2 + wn - 2 x.w = xn + best_score
  float lq = xn[n] + nb1;
  for (int off = 32; off; off >>= 1) lq += __shfl_down(lq, off);
  if ((t & 63) == 0) wred[t >> 6] = lq;
  __syncthreads();
  if (t == 0) atomicAdd(loss_acc, wred[0] + wred[1] + wred[2] + wred[3]);
}

// ---------------- refine2: fp64 exact re-scan of flagged queries + count patch ----------------
__global__ __launch_bounds__(256) void refine2(const float* __restrict__ X,
                                               const float* __restrict__ W,
                                               const int* __restrict__ flagcount,
                                               const int2* __restrict__ flaglist,
                                               float* __restrict__ idx_out,
                                               int* __restrict__ counts) {
  __shared__ double xd[CHAN];
  __shared__ double rv[256];
  __shared__ int    ri[256];
  int t = threadIdx.x;
  int cnt = flagcount[0];
  for (int jj = blockIdx.x; jj < cnt; jj += gridDim.x) {
    __syncthreads();
    int2 e = flaglist[jj];
    int n = e.x, prov = e.y;
    int b = n / S_SP, s = n % S_SP;
    xd[t] = (double)X[(size_t)b * CS + (size_t)t * S_SP + s];
    __syncthreads();

    double best = 1e300;
    int bi = 1 << 30;
    for (int j8 = 0; j8 < 8; ++j8) {
      int k = t * 8 + j8;
      const float* Wp = W + (size_t)k * CHAN;
      double dsum = 0.0;
      for (int d = 0; d < CHAN; ++d) {
        double df = xd[d] - (double)Wp[d];
        dsum = fma(df, df, dsum);
      }
      if (dsum < best) { best = dsum; bi = k; }
    }
    rv[t] = best; ri[t] = bi;
    __syncthreads();
    for (int off = 128; off > 0; off >>= 1) {
      if (t < off) {
        if (rv[t + off] < rv[t] || (rv[t + off] == rv[t] && ri[t + off] < ri[t])) {
          rv[t] = rv[t + off]; ri[t] = ri[t + off];
        }
      }
      __syncthreads();
    }
    if (t == 0) {
      int fin = ri[0];
      idx_out[n] = (float)fin;
      if (fin != prov) {
        atomicAdd(&counts[prov], -1);
        atomicAdd(&counts[fin], 1);
      }
    }
  }
}

// ---------------- emit_og: one-hot ones + quantized gather (ENC pre-zeroed by prep_wx) ----------------
__global__ __launch_bounds__(256) void emit_og(const float* __restrict__ W,
                                               float* __restrict__ outF) {
  __shared__ int sidx[64];
  int t = threadIdx.x;
  int qb = blockIdx.x * 64;
  if (t < 64) sidx[t] = (int)outF[OFF_IDX + qb + t];
  __syncthreads();
  if (t < 64) outF[OFF_ENC + (size_t)(qb + t) * KCODES + sidx[t]] = 1.0f;

  // quantized gather (4 channel-groups x 64 queries)
  int q = t & 63, cg = t >> 6;
  int n = qb + q;
  int idx = sidx[q];
  int b = n / S_SP, s = n % S_SP;   // 13824 % 64 == 0: block never crosses b
  const float* Wp = W + (size_t)idx * CHAN;
  float* qp = outF + OFF_Q + (size_t)b * CS + s;
#pragma unroll 8
  for (int k = 0; k < 64; ++k) {
    int c = cg + (k << 2);
    qp[(size_t)c * S_SP] = Wp[c];
  }
}

// ---------------- finalize ----------------
__global__ __launch_bounds__(256) void finalize(const int* __restrict__ counts,
                                                const float* __restrict__ loss_acc,
                                                float* __restrict__ outF) {
  __shared__ double red[256];
  int t = threadIdx.x;
  double H = 0.0;
  for (int k = t; k < KCODES; k += 256) {
    double p = (double)counts[k] / (double)NQ;
    H += p * log(p + 1e-10);
  }
  red[t] = H;
  __syncthreads();
  for (int off = 128; off > 0; off >>= 1) {
    if (t < off) red[t] += red[t + off];
    __syncthreads();
  }
  if (t == 0) {
    outF[0] = 0.25f * (loss_acc[0] / 7077888.0f);
    outF[OFF_PPL] = (float)exp(-red[0]);
  }
}

extern "C" void kernel_launch(void* const* d_in, const int* in_sizes, int n_in,
                              void* d_out, int out_size, void* d_ws, size_t ws_size,
                              hipStream_t stream) {
  const float* X = (const float*)d_in[0];
  const float* W = (const float*)d_in[1];
  float* outF = (float*)d_out;
  char* ws = (char*)d_ws;
  float* wn        = (float*)ws;                    // 8 KB
  int*   counts    = (int*)(ws + 8192);             // 8 KB   [zeroed by prep_wx]
  float* loss_acc  = (float*)(ws + 16384);          // 4 B    [zeroed by prep_wx]
  int*   flagcount = (int*)(ws + 16388);            // 4 B    [zeroed by prep_wx]
  int2*  flaglist  = (int2*)(ws + 32768);           // 8*NQ = 216 KB
  float* rB1       = (float*)(ws + 262144);         // 2*NQ*4
  int*   rI1       = (int*)(ws + 483328);           // 2*NQ*4
  float* rB2       = (float*)(ws + 704512);         // 2*NQ*4
  float* xn        = (float*)(ws + 925696);         // NQ*4 = 108 KB
  unsigned short* Wh = (unsigned short*)(ws + 1048576);   // 1 MB
  unsigned short* Wl = (unsigned short*)(ws + 2097152);   // 1 MB
  unsigned short* Xh = (unsigned short*)(ws + 3145728);   // 14.16 MB
  unsigned short* Xl = Xh + (size_t)NQ * CHAN;            // 14.16 MB

  prep_wx<<<256 + NQ / 32 + NQ / 16, 256, 0, stream>>>(W, X, Wh, Wl, wn, Xh, Xl, xn,
                                                       (int*)(ws + 8192), outF);
  dist_mfma<<<(NQ / 128) * 2, 256, 0, stream>>>(Xh, Xl, Wh, Wl, wn, rB1, rI1, rB2);
  merge_k<<<NQ / 256, 256, 0, stream>>>(rB1, rI1, rB2, xn, outF + OFF_IDX,
                                        flagcount, flaglist, counts, loss_acc);
  refine2<<<256, 256, 0, stream>>>(X, W, flagcount, flaglist, outF + OFF_IDX, counts);
  emit_og<<<NQ / 64, 256, 0, stream>>>(W, outF);
  finalize<<<1, 256, 0, stream>>>(counts, loss_acc, outF);
}

// Round 18
// 254.205 us; speedup vs baseline: 1.5666x; 1.0124x over previous
//
#include <hip/hip_runtime.h>

#define S_SP   13824        // 24*24*24 spatial
#define CHAN   256
#define NQ     27648        // 2 * 13824
#define KCODES 2048
#define CS     3538944      // CHAN * S_SP
#define OFF_Q   1
#define OFF_PPL 7077889
#define OFF_ENC 7077890LL
#define OFF_IDX 63700994LL

typedef __bf16 bf16x8 __attribute__((ext_vector_type(8)));
typedef float  f32x4  __attribute__((ext_vector_type(4)));
typedef float  f32x16 __attribute__((ext_vector_type(16)));

#define GLOAD_LDS16(g, s)                                                      \
  __builtin_amdgcn_global_load_lds(                                            \
      (const __attribute__((address_space(1))) void*)(g),                      \
      (__attribute__((address_space(3))) void*)(s), 16, 0, 0)

__device__ __forceinline__ unsigned int f2bf(float f) {
  unsigned int u = __float_as_uint(f);
  unsigned int r = u + 0x7FFFu + ((u >> 16) & 1u);   // RNE
  return r >> 16;
}
__device__ __forceinline__ float bf2f(unsigned int h) {
  return __uint_as_float(h << 16);
}
__device__ __forceinline__ void fsplit(float f, unsigned int& hi, unsigned int& lo) {
  hi = f2bf(f);
  float r = f - bf2f(hi);
  lo = f2bf(r);
}

// ---------------- prep_wx: fused W-prep (blocks 0..255) and X-prep (blocks 256..1119) ----------------
__global__ __launch_bounds__(256) void prep_wx(const float* __restrict__ W,
                                               const float* __restrict__ X,
                                               unsigned short* __restrict__ Wh,
                                               unsigned short* __restrict__ Wl,
                                               float* __restrict__ wn,
                                               unsigned short* __restrict__ Xh,
                                               unsigned short* __restrict__ Xl,
                                               float* __restrict__ xn,
                                               int* __restrict__ zero_base) {
  __shared__ float xs[32 * 257];
  int t = threadIdx.x;
  if (blockIdx.x < 256) {
    // ---- W path ----
    if (blockIdx.x == 0) {
      for (int j = t; j < 2050; j += 256) zero_base[j] = 0;
    }
    int g = blockIdx.x * 256 + t;
    int row = g >> 5;
    int d0 = (g & 31) * 8;
    const float* Wp = W + (size_t)row * CHAN + d0;
    float v[8];
    *(float4*)(v) = *(const float4*)Wp;
    *(float4*)(v + 4) = *(const float4*)(Wp + 4);
    float s = 0.f;
    unsigned int h[8], l[8];
#pragma unroll
    for (int j = 0; j < 8; ++j) {
      s = fmaf(v[j], v[j], s);
      fsplit(v[j], h[j], l[j]);
    }
    int4 ph, pl;
    ph.x = (int)(h[0] | (h[1] << 16)); ph.y = (int)(h[2] | (h[3] << 16));
    ph.z = (int)(h[4] | (h[5] << 16)); ph.w = (int)(h[6] | (h[7] << 16));
    pl.x = (int)(l[0] | (l[1] << 16)); pl.y = (int)(l[2] | (l[3] << 16));
    pl.z = (int)(l[4] | (l[5] << 16)); pl.w = (int)(l[6] | (l[7] << 16));
    *(int4*)(Wh + (size_t)row * CHAN + d0) = ph;
    *(int4*)(Wl + (size_t)row * CHAN + d0) = pl;
    for (int off = 16; off; off >>= 1) s += __shfl_down(s, off);
    if ((t & 31) == 0) wn[row] = s;
    return;
  }
  // ---- X path ----
  int qb = (blockIdx.x - 256) * 32;
  int b = qb / S_SP, s0 = qb % S_SP;
  const float* xp = X + (size_t)b * CS + s0;
  int q = t & 31;
  int db = t >> 5;                 // 0..7
  for (int r = 0; r < 32; ++r) {
    int d = db + (r << 3);
    xs[q * 257 + d] = xp[(size_t)d * S_SP + q];
  }
  __syncthreads();
  int row = t >> 3, c8 = t & 7;
  size_t obase = (size_t)(qb + row) * CHAN;
  const float* rp0 = xs + row * 257;
  float ss = 0.f;
#pragma unroll
  for (int j = 0; j < 4; ++j) {
    int d = j * 64 + c8 * 8;
    const float* rp = rp0 + d;
    unsigned int h[8], l[8];
#pragma unroll
    for (int e = 0; e < 8; ++e) {
      float v = rp[e];
      ss = fmaf(v, v, ss);
      fsplit(v, h[e], l[e]);
    }
    int4 ph, pl;
    ph.x = (int)(h[0] | (h[1] << 16)); ph.y = (int)(h[2] | (h[3] << 16));
    ph.z = (int)(h[4] | (h[5] << 16)); ph.w = (int)(h[6] | (h[7] << 16));
    pl.x = (int)(l[0] | (l[1] << 16)); pl.y = (int)(l[2] | (l[3] << 16));
    pl.z = (int)(l[4] | (l[5] << 16)); pl.w = (int)(l[6] | (l[7] << 16));
    *(int4*)(Xh + obase + d) = ph;
    *(int4*)(Xl + obase + d) = pl;
  }
  ss += __shfl_xor(ss, 1);
  ss += __shfl_xor(ss, 2);
  ss += __shfl_xor(ss, 4);
  if (c8 == 0) xn[qb + row] = ss;
}

// ---------------- dist_mfma: 32x32x16 MFMA, LDS-staged, pipelined argmin ----------------
// 4 waves x 32 q = 128 q/block; kg = blockIdx&1 picks 1024-code half; 32 tiles of 32 codes.
// A (X): row = lane&31, k = kc*16 + (lane>>5)*8 + e. B (W): col = lane&31, same k pattern.
// C: col(code) = lane&31, row(query) = (reg&3) + 8*(reg>>2) + 4*(lane>>5)   [m74/m101]
__global__ __launch_bounds__(256, 2) void dist_mfma(const unsigned short* __restrict__ Xh,
                                                    const unsigned short* __restrict__ Xl,
                                                    const unsigned short* __restrict__ Wh,
                                                    const unsigned short* __restrict__ Wl,
                                                    const float* __restrict__ wn,
                                                    float* __restrict__ rB1,
                                                    int* __restrict__ rI1,
                                                    float* __restrict__ rB2) {
  __shared__ __align__(16) unsigned short sW[2][2][8192]; // [buf][hi/lo][kc*512 + lane*8]
  __shared__ float wnl[1024];
  int t = threadIdx.x;
  int w = t >> 6, l = t & 63;
  int lcol = l & 31;        // code column
  int lkg  = l >> 5;        // k-subgroup 0/1
  int kg = blockIdx.x & 1;
  int qb = (blockIdx.x >> 1) * 128;
  int kofs = kg << 10;

  for (int j = t; j < 1024; j += 256) wnl[j] = wn[kofs + j];

  // A fragments: wave owns 32 query rows; 16 k-chunks of K=16
  bf16x8 ah[16], al[16];
  {
    size_t base = (size_t)(qb + w * 32 + lcol) * CHAN + (lkg << 3);
#pragma unroll
    for (int kc = 0; kc < 16; ++kc) {
      ah[kc] = *(const bf16x8*)(Xh + base + kc * 16);
      al[kc] = *(const bf16x8*)(Xl + base + kc * 16);
    }
  }

  float b1[16], b2[16]; int i1[16];
#pragma unroll
  for (int r = 0; r < 16; ++r) { b1[r] = 3.4e38f; b2[r] = 3.4e38f; i1[r] = 0; }

  // wave w stages k-chunks 4w..4w+3 (hi+lo) of the 32-code tile
  auto stage = [&](int buf, int kt) {
    size_t rb = (size_t)(kofs + (kt << 5) + lcol) * CHAN + (lkg << 3);
#pragma unroll
    for (int j = 0; j < 4; ++j) {
      int kc = 4 * w + j;
      GLOAD_LDS16(Wh + rb + kc * 16, &sW[buf][0][kc * 512]);
      GLOAD_LDS16(Wl + rb + kc * 16, &sW[buf][1][kc * 512]);
    }
  };

  auto compute = [&](int cur, f32x16& out) {
    f32x16 a = {0.f,0.f,0.f,0.f,0.f,0.f,0.f,0.f,0.f,0.f,0.f,0.f,0.f,0.f,0.f,0.f};
#pragma unroll
    for (int kc = 0; kc < 16; ++kc) {
      bf16x8 bh = *(const bf16x8*)&sW[cur][0][kc * 512 + l * 8];
      bf16x8 bl = *(const bf16x8*)&sW[cur][1][kc * 512 + l * 8];
      a = __builtin_amdgcn_mfma_f32_32x32x16_bf16(ah[kc], bh, a, 0, 0, 0);
      a = __builtin_amdgcn_mfma_f32_32x32x16_bf16(al[kc], bh, a, 0, 0, 0);
      a = __builtin_amdgcn_mfma_f32_32x32x16_bf16(ah[kc], bl, a, 0, 0, 0);
    }
    out = a;
  };

  auto select = [&](const f32x16& a, int k, float wnk) {
#pragma unroll
    for (int r = 0; r < 16; ++r) {
      float s = fmaf(-2.0f, a[r], wnk);
      bool lt = s < b1[r];
      b2[r] = fminf(b2[r], fmaxf(s, b1[r]));
      b1[r] = lt ? s : b1[r];
      i1[r] = lt ? k : i1[r];
    }
  };

  stage(0, 0);
  __syncthreads();                 // wnl + tile0 ready

  // prologue: compute tile 0 while tile 1 stages
  f32x16 pa;
  int   pk   = kofs + lcol;
  float pwnk = wnl[lcol];
  stage(1, 1);
  compute(0, pa);
  __syncthreads();

  for (int kt = 1; kt < 32; ++kt) {
    int cur = kt & 1;
    if (kt < 31) stage(cur ^ 1, kt + 1);
    f32x16 a;
    compute(cur, a);
    select(pa, pk, pwnk);          // previous tile's selection overlaps this tile's MFMAs
    pa = a;
    pk = kofs + (kt << 5) + lcol;
    pwnk = wnl[(kt << 5) + lcol];
    __syncthreads();
  }
  select(pa, pk, pwnk);

  // reduce across the 32 code-lanes (xor bits 0..4; lkg/row-set invariant)
#pragma unroll
  for (int m = 1; m < 32; m <<= 1) {
#pragma unroll
    for (int r = 0; r < 16; ++r) {
      float ob1 = __shfl_xor(b1[r], m);
      int   oi  = __shfl_xor(i1[r], m);
      float ob2 = __shfl_xor(b2[r], m);
      bool sw = (ob1 < b1[r]) || (ob1 == b1[r] && oi < i1[r]);
      b2[r] = fminf(fmaxf(b1[r], ob1), fminf(b2[r], ob2));
      b1[r] = sw ? ob1 : b1[r];
      i1[r] = sw ? oi : i1[r];
    }
  }
  if (lcol == 0) {
#pragma unroll
    for (int r = 0; r < 16; ++r) {
      int row = (r & 3) + 8 * (r >> 2) + 4 * lkg;
      int q = qb + w * 32 + row;
      size_t o = (size_t)kg * NQ + q;
      rB1[o] = b1[r]; rI1[o] = i1[r]; rB2[o] = b2[r];
    }
  }
}

// ---------------- merge_k: combine kg halves, idx + flags + counts + loss ----------------
__global__ __launch_bounds__(256) void merge_k(const float* __restrict__ rB1,
                                               const int* __restrict__ rI1,
                                               const float* __restrict__ rB2,
                                               const float* __restrict__ xn,
                                               float* __restrict__ idx_out,
                                               int* __restrict__ flagcount,
                                               int2* __restrict__ flaglist,
                                               int* __restrict__ counts,
                                               float* __restrict__ loss_acc) {
  __shared__ float wred[4];
  int t = threadIdx.x;
  int n = blockIdx.x * 256 + t;
  float B1 = rB1[n]; int I1 = rI1[n]; float B2 = rB2[n];
  float c1 = rB1[NQ + n]; int ci = rI1[NQ + n]; float c2 = rB2[NQ + n];
  bool sw = (c1 < B1) || (c1 == B1 && ci < I1);
  float nb2 = fminf(fmaxf(B1, c1), fminf(B2, c2));
  float nb1 = sw ? c1 : B1;
  int   ni  = sw ? ci : I1;
  if (nb2 - nb1 < 0.05f) {
    int slot = atomicAdd(flagcount, 1);
    flaglist[slot] = make_int2(n, ni);
  }
  idx_out[n] = (float)ni;   // provisional if flagged; refine2 overwrites
  atomicAdd(&counts[ni], 1);

  // loss: dist^2 = ||x||^2 + wn - 2 x.w = xn + best_score
  float lq = xn[n] + nb1;
  for (int off = 32; off; off >>= 1) lq += __shfl_down(lq, off);
  if ((t & 63) == 0) wred[t >> 6] = lq;
  __syncthreads();
  if (t == 0) atomicAdd(loss_acc, wred[0] + wred[1] + wred[2] + wred[3]);
}

// ---------------- refine2: fp64 exact re-scan of flagged queries + count patch ----------------
__global__ __launch_bounds__(256) void refine2(const float* __restrict__ X,
                                               const float* __restrict__ W,
                                               const int* __restrict__ flagcount,
                                               const int2* __restrict__ flaglist,
                                               float* __restrict__ idx_out,
                                               int* __restrict__ counts) {
  __shared__ double xd[CHAN];
  __shared__ double rv[256];
  __shared__ int    ri[256];
  int t = threadIdx.x;
  int cnt = flagcount[0];
  for (int jj = blockIdx.x; jj < cnt; jj += gridDim.x) {
    __syncthreads();
    int2 e = flaglist[jj];
    int n = e.x, prov = e.y;
    int b = n / S_SP, s = n % S_SP;
    xd[t] = (double)X[(size_t)b * CS + (size_t)t * S_SP + s];
    __syncthreads();

    double best = 1e300;
    int bi = 1 << 30;
    for (int j8 = 0; j8 < 8; ++j8) {
      int k = t * 8 + j8;
      const float* Wp = W + (size_t)k * CHAN;
      double dsum = 0.0;
      for (int d = 0; d < CHAN; ++d) {
        double df = xd[d] - (double)Wp[d];
        dsum = fma(df, df, dsum);
      }
      if (dsum < best) { best = dsum; bi = k; }
    }
    rv[t] = best; ri[t] = bi;
    __syncthreads();
    for (int off = 128; off > 0; off >>= 1) {
      if (t < off) {
        if (rv[t + off] < rv[t] || (rv[t + off] == rv[t] && ri[t + off] < ri[t])) {
          rv[t] = rv[t + off]; ri[t] = ri[t + off];
        }
      }
      __syncthreads();
    }
    if (t == 0) {
      int fin = ri[0];
      idx_out[n] = (float)fin;
      if (fin != prov) {
        atomicAdd(&counts[prov], -1);
        atomicAdd(&counts[fin], 1);
      }
    }
  }
}

// ---------------- emit_q: one-hot rows (zeros then ones) + quantized gather ----------------
__global__ __launch_bounds__(256) void emit_q(const float* __restrict__ W,
                                              float* __restrict__ outF) {
  __shared__ int sidx[64];
  int t = threadIdx.x;
  int qb = blockIdx.x * 64;
  if (t < 64) sidx[t] = (int)outF[OFF_IDX + qb + t];
  __syncthreads();

  // zero all 64 rows: 2 float4 stores per row per thread, wave-contiguous 1KB
  {
    f32x4 z = {0.f, 0.f, 0.f, 0.f};
    float* rp = outF + OFF_ENC + (size_t)qb * KCODES + t * 4;
#pragma unroll 4
    for (int q = 0; q < 64; ++q) {
      *(f32x4*)rp = z;
      *(f32x4*)(rp + 1024) = z;
      rp += KCODES;
    }
  }
  __syncthreads();   // order zeros before ones
  if (t < 64) outF[OFF_ENC + (size_t)(qb + t) * KCODES + sidx[t]] = 1.0f;

  // quantized gather (4 channel-groups x 64 queries)
  int q = t & 63, cg = t >> 6;
  int n = qb + q;
  int idx = sidx[q];
  int b = n / S_SP, s = n % S_SP;   // 13824 % 64 == 0: block never crosses b
  const float* Wp = W + (size_t)idx * CHAN;
  float* qp = outF + OFF_Q + (size_t)b * CS + s;
#pragma unroll 8
  for (int k = 0; k < 64; ++k) {
    int c = cg + (k << 2);
    qp[(size_t)c * S_SP] = Wp[c];
  }
}

// ---------------- finalize ----------------
__global__ __launch_bounds__(256) void finalize(const int* __restrict__ counts,
                                                const float* __restrict__ loss_acc,
                                                float* __restrict__ outF) {
  __shared__ double red[256];
  int t = threadIdx.x;
  double H = 0.0;
  for (int k = t; k < KCODES; k += 256) {
    double p = (double)counts[k] / (double)NQ;
    H += p * log(p + 1e-10);
  }
  red[t] = H;
  __syncthreads();
  for (int off = 128; off > 0; off >>= 1) {
    if (t < off) red[t] += red[t + off];
    __syncthreads();
  }
  if (t == 0) {
    outF[0] = 0.25f * (loss_acc[0] / 7077888.0f);
    outF[OFF_PPL] = (float)exp(-red[0]);
  }
}

extern "C" void kernel_launch(void* const* d_in, const int* in_sizes, int n_in,
                              void* d_out, int out_size, void* d_ws, size_t ws_size,
                              hipStream_t stream) {
  const float* X = (const float*)d_in[0];
  const float* W = (const float*)d_in[1];
  float* outF = (float*)d_out;
  char* ws = (char*)d_ws;
  float* wn        = (float*)ws;                    // 8 KB
  int*   counts    = (int*)(ws + 8192);             // 8 KB   [zeroed by prep_wx]
  float* loss_acc  = (float*)(ws + 16384);          // 4 B    [zeroed by prep_wx]
  int*   flagcount = (int*)(ws + 16388);            // 4 B    [zeroed by prep_wx]
  int2*  flaglist  = (int2*)(ws + 32768);           // 8*NQ = 216 KB
  float* rB1       = (float*)(ws + 262144);         // 2*NQ*4
  int*   rI1       = (int*)(ws + 483328);           // 2*NQ*4
  float* rB2       = (float*)(ws + 704512);         // 2*NQ*4
  float* xn        = (float*)(ws + 925696);         // NQ*4 = 108 KB
  unsigned short* Wh = (unsigned short*)(ws + 1048576);   // 1 MB
  unsigned short* Wl = (unsigned short*)(ws + 2097152);   // 1 MB
  unsigned short* Xh = (unsigned short*)(ws + 3145728);   // 14.16 MB
  unsigned short* Xl = Xh + (size_t)NQ * CHAN;            // 14.16 MB

  prep_wx<<<256 + NQ / 32, 256, 0, stream>>>(W, X, Wh, Wl, wn, Xh, Xl, xn,
                                             (int*)(ws + 8192));
  dist_mfma<<<(NQ / 128) * 2, 256, 0, stream>>>(Xh, Xl, Wh, Wl, wn, rB1, rI1, rB2);
  merge_k<<<NQ / 256, 256, 0, stream>>>(rB1, rI1, rB2, xn, outF + OFF_IDX,
                                        flagcount, flaglist, counts, loss_acc);
  refine2<<<256, 256, 0, stream>>>(X, W, flagcount, flaglist, outF + OFF_IDX, counts);
  emit_q<<<NQ / 64, 256, 0, stream>>>(W, outF);
  finalize<<<1, 256, 0, stream>>>(counts, loss_acc, outF);
}

// Round 19
// 222.638 us; speedup vs baseline: 1.7887x; 1.1418x over previous
//
#include <hip/hip_runtime.h>

#define S_SP   13824        // 24*24*24 spatial
#define CHAN   256
#define NQ     27648        // 2 * 13824
#define KCODES 2048
#define CS     3538944      // CHAN * S_SP
#define OFF_Q   1
#define OFF_PPL 7077889
#define OFF_ENC 7077890LL
#define OFF_IDX 63700994LL
#define DIST_BLKS 432       // (NQ/128)*2

typedef __bf16 bf16x8 __attribute__((ext_vector_type(8)));
typedef float  f32x4  __attribute__((ext_vector_type(4)));

#define GLOAD_LDS16(g, s)                                                      \
  __builtin_amdgcn_global_load_lds(                                            \
      (const __attribute__((address_space(1))) void*)(g),                      \
      (__attribute__((address_space(3))) void*)(s), 16, 0, 0)

__device__ __forceinline__ unsigned int f2bf(float f) {
  unsigned int u = __float_as_uint(f);
  unsigned int r = u + 0x7FFFu + ((u >> 16) & 1u);   // RNE
  return r >> 16;
}
__device__ __forceinline__ float bf2f(unsigned int h) {
  return __uint_as_float(h << 16);
}
__device__ __forceinline__ void fsplit(float f, unsigned int& hi, unsigned int& lo) {
  hi = f2bf(f);
  float r = f - bf2f(hi);
  lo = f2bf(r);
}

// ---------------- prep_wx: fused W-prep (blocks 0..255) and X-prep (blocks 256..1119) ----------------
__global__ __launch_bounds__(256) void prep_wx(const float* __restrict__ W,
                                               const float* __restrict__ X,
                                               unsigned short* __restrict__ Wh,
                                               unsigned short* __restrict__ Wl,
                                               float* __restrict__ wn,
                                               unsigned short* __restrict__ Xh,
                                               unsigned short* __restrict__ Xl,
                                               float* __restrict__ xn,
                                               int* __restrict__ zero_base) {
  __shared__ float xs[32 * 257];
  int t = threadIdx.x;
  if (blockIdx.x < 256) {
    // ---- W path ----
    if (blockIdx.x == 0) {
      for (int j = t; j < 2050; j += 256) zero_base[j] = 0;
    }
    int g = blockIdx.x * 256 + t;
    int row = g >> 5;
    int d0 = (g & 31) * 8;
    const float* Wp = W + (size_t)row * CHAN + d0;
    float v[8];
    *(float4*)(v) = *(const float4*)Wp;
    *(float4*)(v + 4) = *(const float4*)(Wp + 4);
    float s = 0.f;
    unsigned int h[8], l[8];
#pragma unroll
    for (int j = 0; j < 8; ++j) {
      s = fmaf(v[j], v[j], s);
      fsplit(v[j], h[j], l[j]);
    }
    int4 ph, pl;
    ph.x = (int)(h[0] | (h[1] << 16)); ph.y = (int)(h[2] | (h[3] << 16));
    ph.z = (int)(h[4] | (h[5] << 16)); ph.w = (int)(h[6] | (h[7] << 16));
    pl.x = (int)(l[0] | (l[1] << 16)); pl.y = (int)(l[2] | (l[3] << 16));
    pl.z = (int)(l[4] | (l[5] << 16)); pl.w = (int)(l[6] | (l[7] << 16));
    *(int4*)(Wh + (size_t)row * CHAN + d0) = ph;
    *(int4*)(Wl + (size_t)row * CHAN + d0) = pl;
    for (int off = 16; off; off >>= 1) s += __shfl_down(s, off);
    if ((t & 31) == 0) wn[row] = s;
    return;
  }
  // ---- X path ----
  int qb = (blockIdx.x - 256) * 32;
  int b = qb / S_SP, s0 = qb % S_SP;
  const float* xp = X + (size_t)b * CS + s0;
  int q = t & 31;
  int db = t >> 5;                 // 0..7
  for (int r = 0; r < 32; ++r) {
    int d = db + (r << 3);
    xs[q * 257 + d] = xp[(size_t)d * S_SP + q];
  }
  __syncthreads();
  int row = t >> 3, c8 = t & 7;
  size_t obase = (size_t)(qb + row) * CHAN;
  const float* rp0 = xs + row * 257;
  float ss = 0.f;
#pragma unroll
  for (int j = 0; j < 4; ++j) {
    int d = j * 64 + c8 * 8;
    const float* rp = rp0 + d;
    unsigned int h[8], l[8];
#pragma unroll
    for (int e = 0; e < 8; ++e) {
      float v = rp[e];
      ss = fmaf(v, v, ss);
      fsplit(v, h[e], l[e]);
    }
    int4 ph, pl;
    ph.x = (int)(h[0] | (h[1] << 16)); ph.y = (int)(h[2] | (h[3] << 16));
    ph.z = (int)(h[4] | (h[5] << 16)); ph.w = (int)(h[6] | (h[7] << 16));
    pl.x = (int)(l[0] | (l[1] << 16)); pl.y = (int)(l[2] | (l[3] << 16));
    pl.z = (int)(l[4] | (l[5] << 16)); pl.w = (int)(l[6] | (l[7] << 16));
    *(int4*)(Xh + obase + d) = ph;
    *(int4*)(Xl + obase + d) = pl;
  }
  ss += __shfl_xor(ss, 1);
  ss += __shfl_xor(ss, 2);
  ss += __shfl_xor(ss, 4);
  if (c8 == 0) xn[qb + row] = ss;
}

// ---------------- dist_mfma: r13 16x16 LDS-staged kernel + concurrent ENC-zero blocks ----------------
// Blocks 0..431: distance+argmin. Blocks 432..2159: stream-zero 16 one-hot rows each
// (overlaps dist's idle memory pipe — dist runs at <1% HBM).
__global__ __launch_bounds__(256, 2) void dist_mfma(const unsigned short* __restrict__ Xh,
                                                    const unsigned short* __restrict__ Xl,
                                                    const unsigned short* __restrict__ Wh,
                                                    const unsigned short* __restrict__ Wl,
                                                    const float* __restrict__ wn,
                                                    float* __restrict__ rB1,
                                                    int* __restrict__ rI1,
                                                    float* __restrict__ rB2,
                                                    float* __restrict__ outF) {
  __shared__ __align__(16) unsigned short sW[2][2][4096]; // [buf][hi/lo][chunk*512 + lane*8]
  __shared__ float wnl[1024];
  int t = threadIdx.x;

  if (blockIdx.x >= DIST_BLKS) {
    // ---- ENC zero path ----
    int bid2 = blockIdx.x - DIST_BLKS;
    f32x4 z = {0.f, 0.f, 0.f, 0.f};
    float* rp = outF + OFF_ENC + (size_t)bid2 * 16 * KCODES + t * 4;
#pragma unroll 4
    for (int q = 0; q < 16; ++q) {
      *(f32x4*)rp = z;
      *(f32x4*)(rp + 1024) = z;
      rp += KCODES;
    }
    return;
  }

  int w = t >> 6, l = t & 63;
  int lr = l & 15, lc = l >> 4;
  int kg = blockIdx.x & 1;
  int qb = (blockIdx.x >> 1) * 128;
  int kofs = kg << 10;

  for (int j = t; j < 1024; j += 256) wnl[j] = wn[kofs + j];

  bf16x8 ah[2][8], al[2][8];
#pragma unroll
  for (int s = 0; s < 2; ++s) {
    size_t base = (size_t)(qb + w * 32 + s * 16 + lr) * CHAN + lc * 8;
#pragma unroll
    for (int c = 0; c < 8; ++c) {
      ah[s][c] = *(const bf16x8*)(Xh + base + c * 32);
      al[s][c] = *(const bf16x8*)(Xl + base + c * 32);
    }
  }

  float b1[2][4], b2[2][4]; int i1[2][4];
#pragma unroll
  for (int s = 0; s < 2; ++s)
#pragma unroll
    for (int r = 0; r < 4; ++r) { b1[s][r] = 3.4e38f; b2[s][r] = 3.4e38f; i1[s][r] = 0; }

  auto stage = [&](int buf, int kt) {
    size_t rb = (size_t)(kofs + (kt << 4) + lr) * CHAN + lc * 8;
    GLOAD_LDS16(Wh + rb + w * 32,        &sW[buf][0][w * 512]);
    GLOAD_LDS16(Wh + rb + (w + 4) * 32,  &sW[buf][0][(w + 4) * 512]);
    GLOAD_LDS16(Wl + rb + w * 32,        &sW[buf][1][w * 512]);
    GLOAD_LDS16(Wl + rb + (w + 4) * 32,  &sW[buf][1][(w + 4) * 512]);
  };

  auto compute = [&](int cur, f32x4& o0, f32x4& o1) {
    f32x4 a0 = {0.f, 0.f, 0.f, 0.f}, a1 = {0.f, 0.f, 0.f, 0.f};
#pragma unroll
    for (int c = 0; c < 8; ++c) {
      bf16x8 bh = *(const bf16x8*)&sW[cur][0][c * 512 + (l << 3)];
      bf16x8 bl = *(const bf16x8*)&sW[cur][1][c * 512 + (l << 3)];
      a0 = __builtin_amdgcn_mfma_f32_16x16x32_bf16(ah[0][c], bh, a0, 0, 0, 0);
      a1 = __builtin_amdgcn_mfma_f32_16x16x32_bf16(ah[1][c], bh, a1, 0, 0, 0);
      a0 = __builtin_amdgcn_mfma_f32_16x16x32_bf16(al[0][c], bh, a0, 0, 0, 0);
      a1 = __builtin_amdgcn_mfma_f32_16x16x32_bf16(al[1][c], bh, a1, 0, 0, 0);
      a0 = __builtin_amdgcn_mfma_f32_16x16x32_bf16(ah[0][c], bl, a0, 0, 0, 0);
      a1 = __builtin_amdgcn_mfma_f32_16x16x32_bf16(ah[1][c], bl, a1, 0, 0, 0);
    }
    o0 = a0; o1 = a1;
  };

  auto select = [&](const f32x4& a0, const f32x4& a1, int k, float wnk) {
#pragma unroll
    for (int r = 0; r < 4; ++r) {
      float s0 = fmaf(-2.0f, a0[r], wnk);
      bool lt0 = s0 < b1[0][r];
      b2[0][r] = fminf(b2[0][r], fmaxf(s0, b1[0][r]));
      b1[0][r] = lt0 ? s0 : b1[0][r];
      i1[0][r] = lt0 ? k : i1[0][r];
      float s1 = fmaf(-2.0f, a1[r], wnk);
      bool lt1 = s1 < b1[1][r];
      b2[1][r] = fminf(b2[1][r], fmaxf(s1, b1[1][r]));
      b1[1][r] = lt1 ? s1 : b1[1][r];
      i1[1][r] = lt1 ? k : i1[1][r];
    }
  };

  stage(0, 0);
  __syncthreads();

  // prologue: compute tile 0 while tile 1 stages
  f32x4 pa0, pa1;
  int   pk   = kofs + lr;
  float pwnk = wnl[lr];
  stage(1, 1);
  compute(0, pa0, pa1);
  __syncthreads();

  for (int kt = 1; kt < 64; ++kt) {
    int cur = kt & 1;
    if (kt < 63) stage(cur ^ 1, kt + 1);
    f32x4 a0, a1;
    compute(cur, a0, a1);
    // selection for previous tile — independent of this tile's MFMA chain
    select(pa0, pa1, pk, pwnk);
    pa0 = a0; pa1 = a1;
    pk = kofs + (kt << 4) + lr;
    pwnk = wnl[(kt << 4) + lr];
    __syncthreads();
  }
  select(pa0, pa1, pk, pwnk);

#pragma unroll
  for (int m = 1; m < 16; m <<= 1) {
#pragma unroll
    for (int s = 0; s < 2; ++s)
#pragma unroll
      for (int r = 0; r < 4; ++r) {
        float ob1 = __shfl_xor(b1[s][r], m);
        int   oi  = __shfl_xor(i1[s][r], m);
        float ob2 = __shfl_xor(b2[s][r], m);
        bool sw = (ob1 < b1[s][r]) || (ob1 == b1[s][r] && oi < i1[s][r]);
        b2[s][r] = fminf(fmaxf(b1[s][r], ob1), fminf(b2[s][r], ob2));
        b1[s][r] = sw ? ob1 : b1[s][r];
        i1[s][r] = sw ? oi : i1[s][r];
      }
  }
  if (lr == 0) {
#pragma unroll
    for (int s = 0; s < 2; ++s)
#pragma unroll
      for (int r = 0; r < 4; ++r) {
        int q = qb + w * 32 + s * 16 + lc * 4 + r;
        size_t o = (size_t)kg * NQ + q;
        rB1[o] = b1[s][r]; rI1[o] = i1[s][r]; rB2[o] = b2[s][r];
      }
  }
}

// ---------------- merge_k: combine kg halves, idx + flags + counts + loss ----------------
__global__ __launch_bounds__(256) void merge_k(const float* __restrict__ rB1,
                                               const int* __restrict__ rI1,
                                               const float* __restrict__ rB2,
                                               const float* __restrict__ xn,
                                               float* __restrict__ idx_out,
                                               int* __restrict__ flagcount,
                                               int2* __restrict__ flaglist,
                                               int* __restrict__ counts,
                                               float* __restrict__ loss_acc) {
  __shared__ float wred[4];
  int t = threadIdx.x;
  int n = blockIdx.x * 256 + t;
  float B1 = rB1[n]; int I1 = rI1[n]; float B2 = rB2[n];
  float c1 = rB1[NQ + n]; int ci = rI1[NQ + n]; float c2 = rB2[NQ + n];
  bool sw = (c1 < B1) || (c1 == B1 && ci < I1);
  float nb2 = fminf(fmaxf(B1, c1), fminf(B2, c2));
  float nb1 = sw ? c1 : B1;
  int   ni  = sw ? ci : I1;
  if (nb2 - nb1 < 0.05f) {
    int slot = atomicAdd(flagcount, 1);
    flaglist[slot] = make_int2(n, ni);
  }
  idx_out[n] = (float)ni;   // provisional if flagged; refine2 overwrites
  atomicAdd(&counts[ni], 1);

  // loss: dist^2 = ||x||^2 + wn - 2 x.w = xn + best_score
  float lq = xn[n] + nb1;
  for (int off = 32; off; off >>= 1) lq += __shfl_down(lq, off);
  if ((t & 63) == 0) wred[t >> 6] = lq;
  __syncthreads();
  if (t == 0) atomicAdd(loss_acc, wred[0] + wred[1] + wred[2] + wred[3]);
}

// ---------------- refine2: fp64 exact re-scan of flagged queries + count patch ----------------
__global__ __launch_bounds__(256) void refine2(const float* __restrict__ X,
                                               const float* __restrict__ W,
                                               const int* __restrict__ flagcount,
                                               const int2* __restrict__ flaglist,
                                               float* __restrict__ idx_out,
                                               int* __restrict__ counts) {
  __shared__ double xd[CHAN];
  __shared__ double rv[256];
  __shared__ int    ri[256];
  int t = threadIdx.x;
  int cnt = flagcount[0];
  for (int jj = blockIdx.x; jj < cnt; jj += gridDim.x) {
    __syncthreads();
    int2 e = flaglist[jj];
    int n = e.x, prov = e.y;
    int b = n / S_SP, s = n % S_SP;
    xd[t] = (double)X[(size_t)b * CS + (size_t)t * S_SP + s];
    __syncthreads();

    double best = 1e300;
    int bi = 1 << 30;
    for (int j8 = 0; j8 < 8; ++j8) {
      int k = t * 8 + j8;
      const float* Wp = W + (size_t)k * CHAN;
      double dsum = 0.0;
      for (int d = 0; d < CHAN; ++d) {
        double df = xd[d] - (double)Wp[d];
        dsum = fma(df, df, dsum);
      }
      if (dsum < best) { best = dsum; bi = k; }
    }
    rv[t] = best; ri[t] = bi;
    __syncthreads();
    for (int off = 128; off > 0; off >>= 1) {
      if (t < off) {
        if (rv[t + off] < rv[t] || (rv[t + off] == rv[t] && ri[t + off] < ri[t])) {
          rv[t] = rv[t + off]; ri[t] = ri[t + off];
        }
      }
      __syncthreads();
    }
    if (t == 0) {
      int fin = ri[0];
      idx_out[n] = (float)fin;
      if (fin != prov) {
        atomicAdd(&counts[prov], -1);
        atomicAdd(&counts[fin], 1);
      }
    }
  }
}

// ---------------- emit_og: one-hot ones + quantized gather (ENC zeroed during dist) ----------------
__global__ __launch_bounds__(256) void emit_og(const float* __restrict__ W,
                                               float* __restrict__ outF) {
  __shared__ int sidx[64];
  int t = threadIdx.x;
  int qb = blockIdx.x * 64;
  if (t < 64) sidx[t] = (int)outF[OFF_IDX + qb + t];
  __syncthreads();
  if (t < 64) outF[OFF_ENC + (size_t)(qb + t) * KCODES + sidx[t]] = 1.0f;

  // quantized gather (4 channel-groups x 64 queries)
  int q = t & 63, cg = t >> 6;
  int n = qb + q;
  int idx = sidx[q];
  int b = n / S_SP, s = n % S_SP;   // 13824 % 64 == 0: block never crosses b
  const float* Wp = W + (size_t)idx * CHAN;
  float* qp = outF + OFF_Q + (size_t)b * CS + s;
#pragma unroll 8
  for (int k = 0; k < 64; ++k) {
    int c = cg + (k << 2);
    qp[(size_t)c * S_SP] = Wp[c];
  }
}

// ---------------- finalize ----------------
__global__ __launch_bounds__(256) void finalize(const int* __restrict__ counts,
                                                const float* __restrict__ loss_acc,
                                                float* __restrict__ outF) {
  __shared__ double red[256];
  int t = threadIdx.x;
  double H = 0.0;
  for (int k = t; k < KCODES; k += 256) {
    double p = (double)counts[k] / (double)NQ;
    H += p * log(p + 1e-10);
  }
  red[t] = H;
  __syncthreads();
  for (int off = 128; off > 0; off >>= 1) {
    if (t < off) red[t] += red[t + off];
    __syncthreads();
  }
  if (t == 0) {
    outF[0] = 0.25f * (loss_acc[0] / 7077888.0f);
    outF[OFF_PPL] = (float)exp(-red[0]);
  }
}

extern "C" void kernel_launch(void* const* d_in, const int* in_sizes, int n_in,
                              void* d_out, int out_size, void* d_ws, size_t ws_size,
                              hipStream_t stream) {
  const float* X = (const float*)d_in[0];
  const float* W = (const float*)d_in[1];
  float* outF = (float*)d_out;
  char* ws = (char*)d_ws;
  float* wn        = (float*)ws;                    // 8 KB
  int*   counts    = (int*)(ws + 8192);             // 8 KB   [zeroed by prep_wx]
  float* loss_acc  = (float*)(ws + 16384);          // 4 B    [zeroed by prep_wx]
  int*   flagcount = (int*)(ws + 16388);            // 4 B    [zeroed by prep_wx]
  int2*  flaglist  = (int2*)(ws + 32768);           // 8*NQ = 216 KB
  float* rB1       = (float*)(ws + 262144);         // 2*NQ*4
  int*   rI1       = (int*)(ws + 483328);           // 2*NQ*4
  float* rB2       = (float*)(ws + 704512);         // 2*NQ*4
  float* xn        = (float*)(ws + 925696);         // NQ*4 = 108 KB
  unsigned short* Wh = (unsigned short*)(ws + 1048576);   // 1 MB
  unsigned short* Wl = (unsigned short*)(ws + 2097152);   // 1 MB
  unsigned short* Xh = (unsigned short*)(ws + 3145728);   // 14.16 MB
  unsigned short* Xl = Xh + (size_t)NQ * CHAN;            // 14.16 MB

  prep_wx<<<256 + NQ / 32, 256, 0, stream>>>(W, X, Wh, Wl, wn, Xh, Xl, xn,
                                             (int*)(ws + 8192));
  dist_mfma<<<DIST_BLKS + NQ / 16, 256, 0, stream>>>(Xh, Xl, Wh, Wl, wn,
                                                     rB1, rI1, rB2, outF);
  merge_k<<<NQ / 256, 256, 0, stream>>>(rB1, rI1, rB2, xn, outF + OFF_IDX,
                                        flagcount, flaglist, counts, loss_acc);
  refine2<<<256, 256, 0, stream>>>(X, W, flagcount, flaglist, outF + OFF_IDX, counts);
  emit_og<<<NQ / 64, 256, 0, stream>>>(W, outF);
  finalize<<<1, 256, 0, stream>>>(counts, loss_acc, outF);
}

// Round 20
// 219.430 us; speedup vs baseline: 1.8149x; 1.0146x over previous
//
#include <hip/hip_runtime.h>

#define S_SP   13824        // 24*24*24 spatial
#define CHAN   256
#define NQ     27648        // 2 * 13824
#define KCODES 2048
#define CS     3538944      // CHAN * S_SP
#define OFF_Q   1
#define OFF_PPL 7077889
#define OFF_ENC 7077890LL
#define OFF_IDX 63700994LL
#define DIST_BLKS 432       // (NQ/128)*2

typedef __bf16 bf16x8 __attribute__((ext_vector_type(8)));
typedef float  f32x4  __attribute__((ext_vector_type(4)));

#define GLOAD_LDS16(g, s)                                                      \
  __builtin_amdgcn_global_load_lds(                                            \
      (const __attribute__((address_space(1))) void*)(g),                      \
      (__attribute__((address_space(3))) void*)(s), 16, 0, 0)

__device__ __forceinline__ unsigned int f2bf(float f) {
  unsigned int u = __float_as_uint(f);
  unsigned int r = u + 0x7FFFu + ((u >> 16) & 1u);   // RNE
  return r >> 16;
}
__device__ __forceinline__ float bf2f(unsigned int h) {
  return __uint_as_float(h << 16);
}
__device__ __forceinline__ void fsplit(float f, unsigned int& hi, unsigned int& lo) {
  hi = f2bf(f);
  float r = f - bf2f(hi);
  lo = f2bf(r);
}

// ---------------- prep_wx: fused W-prep (blocks 0..255) and X-prep (blocks 256..1119) ----------------
__global__ __launch_bounds__(256) void prep_wx(const float* __restrict__ W,
                                               const float* __restrict__ X,
                                               unsigned short* __restrict__ Wh,
                                               unsigned short* __restrict__ Wl,
                                               float* __restrict__ wn,
                                               unsigned short* __restrict__ Xh,
                                               unsigned short* __restrict__ Xl,
                                               float* __restrict__ xn,
                                               int* __restrict__ zero_base) {
  __shared__ float xs[32 * 257];
  int t = threadIdx.x;
  if (blockIdx.x < 256) {
    // ---- W path ----
    if (blockIdx.x == 0) {
      for (int j = t; j < 2050; j += 256) zero_base[j] = 0;
    }
    int g = blockIdx.x * 256 + t;
    int row = g >> 5;
    int d0 = (g & 31) * 8;
    const float* Wp = W + (size_t)row * CHAN + d0;
    float v[8];
    *(float4*)(v) = *(const float4*)Wp;
    *(float4*)(v + 4) = *(const float4*)(Wp + 4);
    float s = 0.f;
    unsigned int h[8], l[8];
#pragma unroll
    for (int j = 0; j < 8; ++j) {
      s = fmaf(v[j], v[j], s);
      fsplit(v[j], h[j], l[j]);
    }
    int4 ph, pl;
    ph.x = (int)(h[0] | (h[1] << 16)); ph.y = (int)(h[2] | (h[3] << 16));
    ph.z = (int)(h[4] | (h[5] << 16)); ph.w = (int)(h[6] | (h[7] << 16));
    pl.x = (int)(l[0] | (l[1] << 16)); pl.y = (int)(l[2] | (l[3] << 16));
    pl.z = (int)(l[4] | (l[5] << 16)); pl.w = (int)(l[6] | (l[7] << 16));
    *(int4*)(Wh + (size_t)row * CHAN + d0) = ph;
    *(int4*)(Wl + (size_t)row * CHAN + d0) = pl;
    for (int off = 16; off; off >>= 1) s += __shfl_down(s, off);
    if ((t & 31) == 0) wn[row] = s;
    return;
  }
  // ---- X path ----
  int qb = (blockIdx.x - 256) * 32;
  int b = qb / S_SP, s0 = qb % S_SP;
  const float* xp = X + (size_t)b * CS + s0;
  int q = t & 31;
  int db = t >> 5;                 // 0..7
  for (int r = 0; r < 32; ++r) {
    int d = db + (r << 3);
    xs[q * 257 + d] = xp[(size_t)d * S_SP + q];
  }
  __syncthreads();
  int row = t >> 3, c8 = t & 7;
  size_t obase = (size_t)(qb + row) * CHAN;
  const float* rp0 = xs + row * 257;
  float ss = 0.f;
#pragma unroll
  for (int j = 0; j < 4; ++j) {
    int d = j * 64 + c8 * 8;
    const float* rp = rp0 + d;
    unsigned int h[8], l[8];
#pragma unroll
    for (int e = 0; e < 8; ++e) {
      float v = rp[e];
      ss = fmaf(v, v, ss);
      fsplit(v, h[e], l[e]);
    }
    int4 ph, pl;
    ph.x = (int)(h[0] | (h[1] << 16)); ph.y = (int)(h[2] | (h[3] << 16));
    ph.z = (int)(h[4] | (h[5] << 16)); ph.w = (int)(h[6] | (h[7] << 16));
    pl.x = (int)(l[0] | (l[1] << 16)); pl.y = (int)(l[2] | (l[3] << 16));
    pl.z = (int)(l[4] | (l[5] << 16)); pl.w = (int)(l[6] | (l[7] << 16));
    *(int4*)(Xh + obase + d) = ph;
    *(int4*)(Xl + obase + d) = pl;
  }
  ss += __shfl_xor(ss, 1);
  ss += __shfl_xor(ss, 2);
  ss += __shfl_xor(ss, 4);
  if (c8 == 0) xn[qb + row] = ss;
}

// ---------------- dist_mfma: r13 16x16 LDS-staged kernel + concurrent ENC-zero blocks ----------------
__global__ __launch_bounds__(256, 2) void dist_mfma(const unsigned short* __restrict__ Xh,
                                                    const unsigned short* __restrict__ Xl,
                                                    const unsigned short* __restrict__ Wh,
                                                    const unsigned short* __restrict__ Wl,
                                                    const float* __restrict__ wn,
                                                    float* __restrict__ rB1,
                                                    int* __restrict__ rI1,
                                                    float* __restrict__ rB2,
                                                    float* __restrict__ outF) {
  __shared__ __align__(16) unsigned short sW[2][2][4096]; // [buf][hi/lo][chunk*512 + lane*8]
  __shared__ float wnl[1024];
  int t = threadIdx.x;

  if (blockIdx.x >= DIST_BLKS) {
    // ---- ENC zero path ----
    int bid2 = blockIdx.x - DIST_BLKS;
    f32x4 z = {0.f, 0.f, 0.f, 0.f};
    float* rp = outF + OFF_ENC + (size_t)bid2 * 16 * KCODES + t * 4;
#pragma unroll 4
    for (int q = 0; q < 16; ++q) {
      *(f32x4*)rp = z;
      *(f32x4*)(rp + 1024) = z;
      rp += KCODES;
    }
    return;
  }

  int w = t >> 6, l = t & 63;
  int lr = l & 15, lc = l >> 4;
  int kg = blockIdx.x & 1;
  int qb = (blockIdx.x >> 1) * 128;
  int kofs = kg << 10;

  for (int j = t; j < 1024; j += 256) wnl[j] = wn[kofs + j];

  bf16x8 ah[2][8], al[2][8];
#pragma unroll
  for (int s = 0; s < 2; ++s) {
    size_t base = (size_t)(qb + w * 32 + s * 16 + lr) * CHAN + lc * 8;
#pragma unroll
    for (int c = 0; c < 8; ++c) {
      ah[s][c] = *(const bf16x8*)(Xh + base + c * 32);
      al[s][c] = *(const bf16x8*)(Xl + base + c * 32);
    }
  }

  float b1[2][4], b2[2][4]; int i1[2][4];
#pragma unroll
  for (int s = 0; s < 2; ++s)
#pragma unroll
    for (int r = 0; r < 4; ++r) { b1[s][r] = 3.4e38f; b2[s][r] = 3.4e38f; i1[s][r] = 0; }

  auto stage = [&](int buf, int kt) {
    size_t rb = (size_t)(kofs + (kt << 4) + lr) * CHAN + lc * 8;
    GLOAD_LDS16(Wh + rb + w * 32,        &sW[buf][0][w * 512]);
    GLOAD_LDS16(Wh + rb + (w + 4) * 32,  &sW[buf][0][(w + 4) * 512]);
    GLOAD_LDS16(Wl + rb + w * 32,        &sW[buf][1][w * 512]);
    GLOAD_LDS16(Wl + rb + (w + 4) * 32,  &sW[buf][1][(w + 4) * 512]);
  };

  auto compute = [&](int cur, f32x4& o0, f32x4& o1) {
    f32x4 a0 = {0.f, 0.f, 0.f, 0.f}, a1 = {0.f, 0.f, 0.f, 0.f};
#pragma unroll
    for (int c = 0; c < 8; ++c) {
      bf16x8 bh = *(const bf16x8*)&sW[cur][0][c * 512 + (l << 3)];
      bf16x8 bl = *(const bf16x8*)&sW[cur][1][c * 512 + (l << 3)];
      a0 = __builtin_amdgcn_mfma_f32_16x16x32_bf16(ah[0][c], bh, a0, 0, 0, 0);
      a1 = __builtin_amdgcn_mfma_f32_16x16x32_bf16(ah[1][c], bh, a1, 0, 0, 0);
      a0 = __builtin_amdgcn_mfma_f32_16x16x32_bf16(al[0][c], bh, a0, 0, 0, 0);
      a1 = __builtin_amdgcn_mfma_f32_16x16x32_bf16(al[1][c], bh, a1, 0, 0, 0);
      a0 = __builtin_amdgcn_mfma_f32_16x16x32_bf16(ah[0][c], bl, a0, 0, 0, 0);
      a1 = __builtin_amdgcn_mfma_f32_16x16x32_bf16(ah[1][c], bl, a1, 0, 0, 0);
    }
    o0 = a0; o1 = a1;
  };

  auto select = [&](const f32x4& a0, const f32x4& a1, int k, float wnk) {
#pragma unroll
    for (int r = 0; r < 4; ++r) {
      float s0 = fmaf(-2.0f, a0[r], wnk);
      bool lt0 = s0 < b1[0][r];
      b2[0][r] = fminf(b2[0][r], fmaxf(s0, b1[0][r]));
      b1[0][r] = lt0 ? s0 : b1[0][r];
      i1[0][r] = lt0 ? k : i1[0][r];
      float s1 = fmaf(-2.0f, a1[r], wnk);
      bool lt1 = s1 < b1[1][r];
      b2[1][r] = fminf(b2[1][r], fmaxf(s1, b1[1][r]));
      b1[1][r] = lt1 ? s1 : b1[1][r];
      i1[1][r] = lt1 ? k : i1[1][r];
    }
  };

  stage(0, 0);
  __syncthreads();

  // prologue: compute tile 0 while tile 1 stages
  f32x4 pa0, pa1;
  int   pk   = kofs + lr;
  float pwnk = wnl[lr];
  stage(1, 1);
  compute(0, pa0, pa1);
  __syncthreads();

  for (int kt = 1; kt < 64; ++kt) {
    int cur = kt & 1;
    if (kt < 63) stage(cur ^ 1, kt + 1);
    f32x4 a0, a1;
    compute(cur, a0, a1);
    select(pa0, pa1, pk, pwnk);
    pa0 = a0; pa1 = a1;
    pk = kofs + (kt << 4) + lr;
    pwnk = wnl[(kt << 4) + lr];
    __syncthreads();
  }
  select(pa0, pa1, pk, pwnk);

#pragma unroll
  for (int m = 1; m < 16; m <<= 1) {
#pragma unroll
    for (int s = 0; s < 2; ++s)
#pragma unroll
      for (int r = 0; r < 4; ++r) {
        float ob1 = __shfl_xor(b1[s][r], m);
        int   oi  = __shfl_xor(i1[s][r], m);
        float ob2 = __shfl_xor(b2[s][r], m);
        bool sw = (ob1 < b1[s][r]) || (ob1 == b1[s][r] && oi < i1[s][r]);
        b2[s][r] = fminf(fmaxf(b1[s][r], ob1), fminf(b2[s][r], ob2));
        b1[s][r] = sw ? ob1 : b1[s][r];
        i1[s][r] = sw ? oi : i1[s][r];
      }
  }
  if (lr == 0) {
#pragma unroll
    for (int s = 0; s < 2; ++s)
#pragma unroll
      for (int r = 0; r < 4; ++r) {
        int q = qb + w * 32 + s * 16 + lc * 4 + r;
        size_t o = (size_t)kg * NQ + q;
        rB1[o] = b1[s][r]; rI1[o] = i1[s][r]; rB2[o] = b2[s][r];
      }
  }
}

// ---------------- emit_all: kg-merge + idx + flags + counts + loss + ones + gather ----------------
// 432 blocks x 64 queries. Provisional idx everywhere; refine_patch fixes flagged.
__global__ __launch_bounds__(256) void emit_all(const float* __restrict__ rB1,
                                                const int* __restrict__ rI1,
                                                const float* __restrict__ rB2,
                                                const float* __restrict__ xn,
                                                const float* __restrict__ W,
                                                float* __restrict__ outF,
                                                int* __restrict__ flagcount,
                                                int2* __restrict__ flaglist,
                                                int* __restrict__ counts,
                                                float* __restrict__ loss_acc) {
  __shared__ int sidx[64];
  int t = threadIdx.x;
  int qb = blockIdx.x * 64;

  if (t < 64) {
    int n = qb + t;
    float B1 = rB1[n]; int I1 = rI1[n]; float B2 = rB2[n];
    float c1 = rB1[NQ + n]; int ci = rI1[NQ + n]; float c2 = rB2[NQ + n];
    bool sw = (c1 < B1) || (c1 == B1 && ci < I1);
    float nb2 = fminf(fmaxf(B1, c1), fminf(B2, c2));
    float nb1 = sw ? c1 : B1;
    int   ni  = sw ? ci : I1;
    if (nb2 - nb1 < 0.05f) {
      int slot = atomicAdd(flagcount, 1);
      flaglist[slot] = make_int2(n, ni);
    }
    sidx[t] = ni;
    outF[OFF_IDX + n] = (float)ni;            // provisional if flagged
    atomicAdd(&counts[ni], 1);
    outF[OFF_ENC + (size_t)n * KCODES + ni] = 1.0f;

    // loss partial (wave 0 only; lanes 0..63)
    float lq = xn[n] + nb1;
    for (int off = 32; off; off >>= 1) lq += __shfl_down(lq, off);
    if (t == 0) atomicAdd(loss_acc, lq);
  }
  __syncthreads();

  // quantized gather (4 channel-groups x 64 queries)
  int q = t & 63, cg = t >> 6;
  int n = qb + q;
  int idx = sidx[q];
  int b = n / S_SP, s = n % S_SP;   // 13824 % 64 == 0: block never crosses b
  const float* Wp = W + (size_t)idx * CHAN;
  float* qp = outF + OFF_Q + (size_t)b * CS + s;
#pragma unroll 8
  for (int k = 0; k < 64; ++k) {
    int c = cg + (k << 2);
    qp[(size_t)c * S_SP] = Wp[c];
  }
}

// ---------------- refine_patch: fp64 exact re-scan of flagged queries, patch all outputs ----------------
__global__ __launch_bounds__(256) void refine_patch(const float* __restrict__ X,
                                                    const float* __restrict__ W,
                                                    const int* __restrict__ flagcount,
                                                    const int2* __restrict__ flaglist,
                                                    float* __restrict__ outF,
                                                    int* __restrict__ counts) {
  __shared__ double xd[CHAN];
  __shared__ double rv[256];
  __shared__ int    ri[256];
  int t = threadIdx.x;
  int cnt = flagcount[0];
  for (int jj = blockIdx.x; jj < cnt; jj += gridDim.x) {
    __syncthreads();
    int2 e = flaglist[jj];
    int n = e.x, prov = e.y;
    int b = n / S_SP, s = n % S_SP;
    xd[t] = (double)X[(size_t)b * CS + (size_t)t * S_SP + s];
    __syncthreads();

    double best = 1e300;
    int bi = 1 << 30;
    for (int j8 = 0; j8 < 8; ++j8) {
      int k = t * 8 + j8;
      const float* Wp = W + (size_t)k * CHAN;
      double dsum = 0.0;
      for (int d = 0; d < CHAN; ++d) {
        double df = xd[d] - (double)Wp[d];
        dsum = fma(df, df, dsum);
      }
      if (dsum < best) { best = dsum; bi = k; }
    }
    rv[t] = best; ri[t] = bi;
    __syncthreads();
    for (int off = 128; off > 0; off >>= 1) {
      if (t < off) {
        if (rv[t + off] < rv[t] || (rv[t + off] == rv[t] && ri[t + off] < ri[t])) {
          rv[t] = rv[t + off]; ri[t] = ri[t + off];
        }
      }
      __syncthreads();
    }
    int fin = ri[0];
    __syncthreads();
    if (fin != prov) {
      if (t == 0) {
        outF[OFF_IDX + n] = (float)fin;
        atomicAdd(&counts[prov], -1);
        atomicAdd(&counts[fin], 1);
        float* row = outF + OFF_ENC + (size_t)n * KCODES;
        row[prov] = 0.0f;
        row[fin]  = 1.0f;
      }
      // re-gather quantized for this query (one channel per thread)
      float* qp = outF + OFF_Q + (size_t)b * CS + s;
      qp[(size_t)t * S_SP] = W[(size_t)fin * CHAN + t];
    }
  }
}

// ---------------- finalize ----------------
__global__ __launch_bounds__(256) void finalize(const int* __restrict__ counts,
                                                const float* __restrict__ loss_acc,
                                                float* __restrict__ outF) {
  __shared__ double red[256];
  int t = threadIdx.x;
  double H = 0.0;
  for (int k = t; k < KCODES; k += 256) {
    double p = (double)counts[k] / (double)NQ;
    H += p * log(p + 1e-10);
  }
  red[t] = H;
  __syncthreads();
  for (int off = 128; off > 0; off >>= 1) {
    if (t < off) red[t] += red[t + off];
    __syncthreads();
  }
  if (t == 0) {
    outF[0] = 0.25f * (loss_acc[0] / 7077888.0f);
    outF[OFF_PPL] = (float)exp(-red[0]);
  }
}

extern "C" void kernel_launch(void* const* d_in, const int* in_sizes, int n_in,
                              void* d_out, int out_size, void* d_ws, size_t ws_size,
                              hipStream_t stream) {
  const float* X = (const float*)d_in[0];
  const float* W = (const float*)d_in[1];
  float* outF = (float*)d_out;
  char* ws = (char*)d_ws;
  float* wn        = (float*)ws;                    // 8 KB
  int*   counts    = (int*)(ws + 8192);             // 8 KB   [zeroed by prep_wx]
  float* loss_acc  = (float*)(ws + 16384);          // 4 B    [zeroed by prep_wx]
  int*   flagcount = (int*)(ws + 16388);            // 4 B    [zeroed by prep_wx]
  int2*  flaglist  = (int2*)(ws + 32768);           // 8*NQ = 216 KB
  float* rB1       = (float*)(ws + 262144);         // 2*NQ*4
  int*   rI1       = (int*)(ws + 483328);           // 2*NQ*4
  float* rB2       = (float*)(ws + 704512);         // 2*NQ*4
  float* xn        = (float*)(ws + 925696);         // NQ*4 = 108 KB
  unsigned short* Wh = (unsigned short*)(ws + 1048576);   // 1 MB
  unsigned short* Wl = (unsigned short*)(ws + 2097152);   // 1 MB
  unsigned short* Xh = (unsigned short*)(ws + 3145728);   // 14.16 MB
  unsigned short* Xl = Xh + (size_t)NQ * CHAN;            // 14.16 MB

  prep_wx<<<256 + NQ / 32, 256, 0, stream>>>(W, X, Wh, Wl, wn, Xh, Xl, xn,
                                             (int*)(ws + 8192));
  dist_mfma<<<DIST_BLKS + NQ / 16, 256, 0, stream>>>(Xh, Xl, Wh, Wl, wn,
                                                     rB1, rI1, rB2, outF);
  emit_all<<<NQ / 64, 256, 0, stream>>>(rB1, rI1, rB2, xn, W, outF,
                                        flagcount, flaglist, counts, loss_acc);
  refine_patch<<<256, 256, 0, stream>>>(X, W, flagcount, flaglist, outF, counts);
  finalize<<<1, 256, 0, stream>>>(counts, loss_acc, outF);
}